// Round 21
// baseline (72.000 us; speedup 1.0000x reference)
//
#include <hip/hip_runtime.h>
#include <hip/hip_bf16.h>
#include <math.h>

#define B_ 8
#define T_ 256
#define LQ_ 20
#define LC_ 10
#define DIM_ 128
#define N_ 257            // T+1
#define NN_ (B_*N_)       // 2056

// NOTE: parameter must NOT be named 'w'/'x'/'y'/'z' (R12 preprocessor trap).
#define FMA4(a, s, ww) { (a).x += (s)*(ww).x; (a).y += (s)*(ww).y; (a).z += (s)*(ww).z; (a).w += (s)*(ww).w; }

// ---------------- kNODE: R13/R20-proven node pipeline (frozen) ---------------
__global__ __launch_bounds__(512) void kNODE(
    const float* __restrict__ video, const float* __restrict__ Wv,
    const float* __restrict__ bvp,
    const float* __restrict__ We, const float* __restrict__ be,
    const float* __restrict__ vmask,
    const int* __restrict__ word_ids, const int* __restrict__ char_ids,
    const float* __restrict__ word_emb, const float* __restrict__ char_emb,
    const float* __restrict__ W_embed, const float* __restrict__ b_embed,
    const float* __restrict__ q_mask,
    const float* __restrict__ Wq, const float* __restrict__ bq,
    const float* __restrict__ Wk, const float* __restrict__ bk,
    const float* __restrict__ Wvv, const float* __restrict__ bval,
    const float* __restrict__ Ws, const float* __restrict__ bs,
    float* __restrict__ q, float* __restrict__ k,
    float* __restrict__ v, float* __restrict__ sk,
    float* __restrict__ eq)
{
  __shared__ __align__(16) float smem_f[19008];
  float4* ps4 = reinterpret_cast<float4*>(smem_f);
  float* hl = smem_f + 16896;
  float* xe = smem_f + 17952;
  const int blk = blockIdx.x, tid = threadIdx.x;
  const float* Wm[4] = {Wq, Wk, Wvv, Ws};
  const float* bm[4] = {bq, bk, bval, bs};
  float* om[4] = {q, k, v, sk};

  if (blk < 256) {
    const int r0 = blk * 8;
    {
      const float4* src = reinterpret_cast<const float4*>(video + (size_t)r0 * 1024);
      #pragma unroll
      for (int i = 0; i < 4; ++i) {
        const int idx4 = tid + i * 512;
        const int r = idx4 >> 8, f = idx4 & 255;
        *reinterpret_cast<float4*>(&smem_f[r * 1028 + f * 4]) = src[r * 256 + f];
      }
    }
    __syncthreads();
    const int c4 = tid & 31, ks = tid >> 5;
    float4 acc[8];
    #pragma unroll
    for (int r = 0; r < 8; ++r) acc[r] = float4{0.f, 0.f, 0.f, 0.f};
    {
      const float4* W4 = reinterpret_cast<const float4*>(Wv) + c4;
      for (int kc = 0; kc < 16; ++kc) {
        const int k0 = ks * 64 + kc * 4;
        const float4 w0 = W4[(size_t)(k0 + 0) * 32];
        const float4 w1 = W4[(size_t)(k0 + 1) * 32];
        const float4 w2 = W4[(size_t)(k0 + 2) * 32];
        const float4 w3 = W4[(size_t)(k0 + 3) * 32];
        #pragma unroll
        for (int r = 0; r < 8; ++r) {
          const float4 rv = *reinterpret_cast<const float4*>(&smem_f[r * 1028 + k0]);
          FMA4(acc[r], rv.x, w0); FMA4(acc[r], rv.y, w1);
          FMA4(acc[r], rv.z, w2); FMA4(acc[r], rv.w, w3);
        }
      }
    }
    __syncthreads();
    #pragma unroll
    for (int r = 0; r < 8; ++r) ps4[(ks * 8 + r) * 33 + c4] = acc[r];
    __syncthreads();
    if (tid < 256) {
      const int r = tid >> 5, c = tid & 31;
      float4 s = reinterpret_cast<const float4*>(bvp)[c];
      #pragma unroll
      for (int ke = 0; ke < 16; ++ke) {
        const float4 p = ps4[(ke * 8 + r) * 33 + c];
        s.x += p.x; s.y += p.y; s.z += p.z; s.w += p.w;
      }
      *reinterpret_cast<float4*>(&hl[r * 132 + c * 4]) = s;
    }
    __syncthreads();
    #pragma unroll
    for (int r = 0; r < 8; ++r) acc[r] = float4{0.f, 0.f, 0.f, 0.f};
    {
      const float4* We4 = reinterpret_cast<const float4*>(We) + c4;
      #pragma unroll
      for (int kc = 0; kc < 2; ++kc) {
        const int k0 = ks * 8 + kc * 4;
        const float4 w0 = We4[(size_t)(k0 + 0) * 32];
        const float4 w1 = We4[(size_t)(k0 + 1) * 32];
        const float4 w2 = We4[(size_t)(k0 + 2) * 32];
        const float4 w3 = We4[(size_t)(k0 + 3) * 32];
        #pragma unroll
        for (int r = 0; r < 8; ++r) {
          const float4 rv = *reinterpret_cast<const float4*>(&hl[r * 132 + k0]);
          FMA4(acc[r], rv.x, w0); FMA4(acc[r], rv.y, w1);
          FMA4(acc[r], rv.z, w2); FMA4(acc[r], rv.w, w3);
        }
      }
    }
    #pragma unroll
    for (int r = 0; r < 8; ++r) ps4[(ks * 8 + r) * 33 + c4] = acc[r];
    __syncthreads();
    if (tid < 256) {
      const int r = tid >> 5, c = tid & 31;
      float4 s = reinterpret_cast<const float4*>(be)[c];
      #pragma unroll
      for (int ke = 0; ke < 16; ++ke) {
        const float4 p = ps4[(ke * 8 + r) * 33 + c];
        s.x += p.x; s.y += p.y; s.z += p.z; s.w += p.w;
      }
      const float mk = vmask[r0 + r];
      s.x = fmaxf(s.x, 0.f) * mk; s.y = fmaxf(s.y, 0.f) * mk;
      s.z = fmaxf(s.z, 0.f) * mk; s.w = fmaxf(s.w, 0.f) * mk;
      *reinterpret_cast<float4*>(&xe[r * 132 + c * 4]) = s;
    }
    __syncthreads();
    const int m = ks >> 2, keP = ks & 3;
    #pragma unroll
    for (int r = 0; r < 8; ++r) acc[r] = float4{0.f, 0.f, 0.f, 0.f};
    {
      const float4* Wp4 = reinterpret_cast<const float4*>(Wm[m]) + c4;
      #pragma unroll
      for (int kc = 0; kc < 8; ++kc) {
        const int k0 = keP * 32 + kc * 4;
        const float4 w0 = Wp4[(size_t)(k0 + 0) * 32];
        const float4 w1 = Wp4[(size_t)(k0 + 1) * 32];
        const float4 w2 = Wp4[(size_t)(k0 + 2) * 32];
        const float4 w3 = Wp4[(size_t)(k0 + 3) * 32];
        #pragma unroll
        for (int r = 0; r < 8; ++r) {
          const float4 rv = *reinterpret_cast<const float4*>(&xe[r * 132 + k0]);
          FMA4(acc[r], rv.x, w0); FMA4(acc[r], rv.y, w1);
          FMA4(acc[r], rv.z, w2); FMA4(acc[r], rv.w, w3);
        }
      }
    }
    #pragma unroll
    for (int r = 0; r < 8; ++r) ps4[(ks * 8 + r) * 33 + c4] = acc[r];
    __syncthreads();
    #pragma unroll
    for (int it = 0; it < 2; ++it) {
      const int id = tid + it * 512;
      const int mm = id >> 8, r = (id >> 5) & 7, c = id & 31;
      float4 s = reinterpret_cast<const float4*>(bm[mm])[c];
      #pragma unroll
      for (int ke = 0; ke < 4; ++ke) {
        const float4 p = ps4[((mm * 4 + ke) * 8 + r) * 33 + c];
        s.x += p.x; s.y += p.y; s.z += p.z; s.w += p.w;
      }
      const int vr = r0 + r;
      const int node = (vr >> 8) * 257 + 1 + (vr & 255);
      *reinterpret_cast<float4*>(om[mm] + (size_t)node * 128 + 4 * c) = s;
    }
  } else {
    const int qi = blk - 256;
    const int b = qi / 20, lq = qi - b * 20;
    float* emb = smem_f;          // [352]
    float* ps  = emb + 352;       // [2][128]
    float* hq  = emb + 608;       // [128]
    float* pe  = emb + 736;       // [2][128]
    const int wid = word_ids[b * LQ_ + lq];
    for (int m2 = tid; m2 < 300; m2 += 512) emb[m2] = word_emb[(size_t)wid * 300 + m2];
    if (tid < 50) {
      float s = 0.f;
      #pragma unroll
      for (int l = 0; l < 10; ++l) {
        const int cid = char_ids[(b * LQ_ + lq) * 10 + l];
        s += char_emb[cid * 50 + tid];
      }
      emb[300 + tid] = s * 0.1f;
    }
    __syncthreads();
    const int j = tid & 127, half = tid >> 7;
    if (tid < 256) {
      float a = 0.f;
      const float* Wcol = W_embed + (size_t)(half * 175) * 128 + j;
      const float* eh = emb + half * 175;
      #pragma unroll 5
      for (int m2 = 0; m2 < 175; ++m2) a += eh[m2] * Wcol[(size_t)m2 * 128];
      ps[half * 128 + j] = a;
    }
    __syncthreads();
    if (tid < 128) hq[tid] = ps[tid] + ps[128 + tid] + b_embed[tid];
    __syncthreads();
    if (tid < 256) {
      float e = 0.f;
      #pragma unroll 8
      for (int kk = 0; kk < 64; ++kk)
        e += hq[half * 64 + kk] * We[(half * 64 + kk) * 128 + j];
      pe[half * 128 + j] = e;
    }
    __syncthreads();
    if (tid < 128) {
      float ev = pe[tid] + pe[128 + tid] + be[tid];
      ev = fmaxf(ev, 0.f) * q_mask[b * LQ_ + lq];
      eq[(size_t)qi * 128 + tid] = ev;
    }
  }
}

// ---------------- edge multiplicity (verified round 1) -----------------------
__device__ __forceinline__ float cntf(int dnode, int s) {
  if (dnode == 256) return (s == 0 ? 1.f : 0.f) + (s == 255 ? 1.f : 0.f);
  float c = (s != dnode) ? 1.f : 0.f;          // semantic all-pairs (nodes 0..255)
  if (s == 0) c += 1.f;                        // query->segment
  if (s == dnode - 1) c += 2.f;                // qe chain + temporal h=1 fwd
  if (s == dnode + 1 && dnode <= 254) c += 1.f;// temporal h=1 bwd
  if (s == dnode - 2 && dnode >= 2) c += 1.f;  // temporal h=2 fwd
  if (s == dnode + 2 && dnode <= 253) c += 1.f;// temporal h=2 bwd
  return c;
}

// ---------------- kATTN3: full-s scalar-logit attention + logits (no kRED) ---
// grid (16 dtiles x16 dst, 8 b) = 128 blocks, 256 thr.
// thread = (sh=tid>>7 half of each 64-s chunk, dd=(tid>>3)&15, h=tid&7).
// 4 chunks of 64 staged K/V rows; node-0 K/V recomputed in chunk 0; per-(s,h)
// V-dot scalars (R20-verified); epilogue h-reduce + skip-dot + out.
__global__ __launch_bounds__(256) void kATTN3(
    const float* __restrict__ q, const float* __restrict__ k,
    const float* __restrict__ v, const float* __restrict__ eq,
    const float* __restrict__ Wk, const float* __restrict__ bk,
    const float* __restrict__ Wvv, const float* __restrict__ bval,
    const float* __restrict__ sk,
    const float* __restrict__ W_start, const float* __restrict__ b_start,
    const float* __restrict__ W_end, const float* __restrict__ b_end,
    float* __restrict__ out)
{
  __shared__ float Kl[64][128];     // 32 KB
  __shared__ float Vl[64][128];     // 32 KB
  __shared__ float m0[128];
  __shared__ float wstl[128], wenl[128];
  __shared__ float vstl[64][8], venl[64][8];
  __shared__ float part[2][16][8][3];
  __shared__ float attst[16], atten[16];
  __shared__ float red[16][2][2];
  const int d0 = blockIdx.x * 16;
  const int b  = blockIdx.y;
  const int tid = threadIdx.x;
  const int base = b * 257;

  if (tid < 128) {                   // node-0 mean + Wst/Wen LDS copies
    float s = 0.f;
    #pragma unroll 4
    for (int lq = 0; lq < LQ_; ++lq) s += eq[((size_t)b * LQ_ + lq) * 128 + tid];
    m0[tid] = s * (1.f / LQ_);
    wstl[tid] = W_start[tid];
    wenl[tid] = W_end[tid];
  }
  const int sh = tid >> 7, dd = (tid >> 3) & 15, h = tid & 7;
  const int dnode = d0 + dd + 1;
  const float* qrow = q + (size_t)(base + dnode) * 128 + h * 16;
  const float4 qq0 = *(const float4*)(qrow + 0);
  const float4 qq1 = *(const float4*)(qrow + 4);
  const float4 qq2 = *(const float4*)(qrow + 8);
  const float4 qq3 = *(const float4*)(qrow + 12);

  float den = 0.f, nst = 0.f, nen = 0.f;
  for (int c = 0; c < 4; ++c) {
    const int s0 = c * 64;
    __syncthreads();                 // prior chunk reads done; m0/wst ready (c==0)
    {
      const float4* ksrc = reinterpret_cast<const float4*>(k + (size_t)(base + s0) * 128);
      const float4* vsrc = reinterpret_cast<const float4*>(v + (size_t)(base + s0) * 128);
      float4* kd = reinterpret_cast<float4*>(Kl);
      float4* vd = reinterpret_cast<float4*>(Vl);
      #pragma unroll
      for (int i = 0; i < 8; ++i) {
        kd[tid + i * 256] = ksrc[tid + i * 256];
        vd[tid + i * 256] = vsrc[tid + i * 256];
      }
    }
    __syncthreads();
    if (c == 0) {                    // overwrite row 0 with node-0 K/V
      const int j = tid & 127, half = tid >> 7;
      const float* W = half ? Wvv : Wk;
      float acc = half ? bval[j] : bk[j];
      #pragma unroll 8
      for (int kk = 0; kk < 128; ++kk) acc += m0[kk] * W[kk * 128 + j];
      if (half) Vl[0][j] = acc; else Kl[0][j] = acc;
    }
    __syncthreads();
    {                                // per-(s,h) V·Wst / V·Wen scalars
      const int rv = tid >> 3, hv = tid & 7;
      #pragma unroll
      for (int r2 = 0; r2 < 2; ++r2) {
        const int row = rv + r2 * 32;
        const float* vr = &Vl[row][hv * 16];
        const float* ws = &wstl[hv * 16];
        const float* we = &wenl[hv * 16];
        float a = 0.f, e = 0.f;
        #pragma unroll
        for (int i = 0; i < 16; ++i) { a += vr[i] * ws[i]; e += vr[i] * we[i]; }
        vstl[row][hv] = a; venl[row][hv] = e;
      }
    }
    __syncthreads();
    #pragma unroll 4
    for (int si = 0; si < 32; ++si) {
      const int sl = sh * 32 + si;
      const float* krow = &Kl[sl][h * 16];
      const float4 k0 = *(const float4*)(krow + 0);
      const float4 k1 = *(const float4*)(krow + 4);
      const float4 k2 = *(const float4*)(krow + 8);
      const float4 k3 = *(const float4*)(krow + 12);
      float dt = qq0.x*k0.x + qq0.y*k0.y + qq0.z*k0.z + qq0.w*k0.w
               + qq1.x*k1.x + qq1.y*k1.y + qq1.z*k1.z + qq1.w*k1.w
               + qq2.x*k2.x + qq2.y*k2.y + qq2.z*k2.z + qq2.w*k2.w
               + qq3.x*k3.x + qq3.y*k3.y + qq3.z*k3.z + qq3.w*k3.w;
      const float cc = cntf(dnode, s0 + sl);
      const float pw = cc * __expf(dt * 0.25f);
      den += pw;
      nst += pw * vstl[sl][h];
      nen += pw * venl[sl][h];
    }
  }
  part[sh][dd][h][0] = nst;
  part[sh][dd][h][1] = nen;
  part[sh][dd][h][2] = den;
  __syncthreads();
  if (tid < 128) {                   // combine sh halves, /den, h-reduce
    const int dd2 = tid >> 3, h2 = tid & 7;
    const float n1 = part[0][dd2][h2][0] + part[1][dd2][h2][0];
    const float n2 = part[0][dd2][h2][1] + part[1][dd2][h2][1];
    const float dn = part[0][dd2][h2][2] + part[1][dd2][h2][2];
    float rst = n1 / (dn + 1e-16f);
    float ren = n2 / (dn + 1e-16f);
    #pragma unroll
    for (int off = 1; off < 8; off <<= 1) {
      rst += __shfl_xor(rst, off);
      ren += __shfl_xor(ren, off);
    }
    if (h2 == 0) { attst[dd2] = rst; atten[dd2] = ren; }
  }
  __syncthreads();
  {                                  // skip-dot (kRED verbatim) + out
    const int jB = tid & 127, shB = tid >> 7;
    const float wst = wstl[jB], wen = wenl[jB];
    #pragma unroll
    for (int dd8 = 0; dd8 < 8; ++dd8) {
      const int ddx = shB * 8 + dd8;
      const int dst = d0 + ddx;
      const float o = sk[(size_t)(base + dst + 1) * 128 + jB];
      float psum = o * wst, pesum = o * wen;
      #pragma unroll
      for (int off = 1; off < 64; off <<= 1) {
        psum += __shfl_xor(psum, off);
        pesum += __shfl_xor(pesum, off);
      }
      if ((tid & 63) == 0) { red[ddx][jB >> 6][0] = psum; red[ddx][jB >> 6][1] = pesum; }
    }
  }
  __syncthreads();
  if (tid < 16) {
    out[b * 256 + d0 + tid]        = red[tid][0][0] + red[tid][1][0] + attst[tid] + b_start[0];
    out[2048 + b * 256 + d0 + tid] = red[tid][0][1] + red[tid][1][1] + atten[tid] + b_end[0];
  }
}

extern "C" void kernel_launch(void* const* d_in, const int* in_sizes, int n_in,
                              void* d_out, int out_size, void* d_ws, size_t ws_size,
                              hipStream_t stream) {
  const int*   word_ids = (const int*)d_in[0];
  const int*   char_ids = (const int*)d_in[1];
  const float* video    = (const float*)d_in[2];
  const float* v_mask   = (const float*)d_in[3];
  const float* q_mask   = (const float*)d_in[4];
  const float* word_emb = (const float*)d_in[5];
  const float* char_emb = (const float*)d_in[6];
  const float* W_embed  = (const float*)d_in[7];
  const float* b_embed  = (const float*)d_in[8];
  const float* W_vproj  = (const float*)d_in[9];
  const float* b_vproj  = (const float*)d_in[10];
  const float* W_enc    = (const float*)d_in[11];
  const float* b_enc    = (const float*)d_in[12];
  const float* Wq       = (const float*)d_in[13];
  const float* bq       = (const float*)d_in[14];
  const float* Wk       = (const float*)d_in[15];
  const float* bk       = (const float*)d_in[16];
  const float* Wv       = (const float*)d_in[17];
  const float* bv       = (const float*)d_in[18];
  const float* Wskip    = (const float*)d_in[19];
  const float* bskip    = (const float*)d_in[20];
  const float* W_start  = (const float*)d_in[21];
  const float* b_start  = (const float*)d_in[22];
  const float* W_end    = (const float*)d_in[23];
  const float* b_end    = (const float*)d_in[24];

  float* q     = (float*)d_ws;
  float* k     = q  + NN_ * DIM_;
  float* v     = k  + NN_ * DIM_;
  float* sk    = v  + NN_ * DIM_;
  float* eq    = sk + NN_ * DIM_;                    // 160*128

  hipLaunchKernelGGL(kNODE, dim3(416), dim3(512), 0, stream,
    video, W_vproj, b_vproj, W_enc, b_enc, v_mask,
    word_ids, char_ids, word_emb, char_emb, W_embed, b_embed, q_mask,
    Wq, bq, Wk, bk, Wv, bv, Wskip, bskip, q, k, v, sk, eq);
  hipLaunchKernelGGL(kATTN3, dim3(16, 8), dim3(256), 0, stream,
    q, k, v, eq, Wk, bk, Wv, bv, sk, W_start, b_start, W_end, b_end,
    (float*)d_out);
}

// Round 22
// 58.666 us; speedup vs baseline: 1.2273x; 1.2273x over previous
//
#include <hip/hip_runtime.h>
#include <hip/hip_bf16.h>
#include <math.h>

#define B_ 8
#define T_ 256
#define LQ_ 20
#define LC_ 10
#define DIM_ 128
#define N_ 257            // T+1
#define NN_ (B_*N_)       // 2056

// NOTE: parameter must NOT be named 'w'/'x'/'y'/'z' (R12 preprocessor trap).
#define FMA4(a, s, ww) { (a).x += (s)*(ww).x; (a).y += (s)*(ww).y; (a).z += (s)*(ww).z; (a).w += (s)*(ww).w; }

// ---------------- kNODE: R13-proven node pipeline (champion config) ----------
// 512 thr. Thread = (c4 0..31, ks 0..15); owns all 8 rows -> 32 FMA per
// 16B W-load; W read once per block. K-split partials alias the dead video
// staging buffer (union) -> 76 KB LDS, 2 blocks/CU.
// blocks 0..255: 8 video rows.  blocks 256..415: query row -> eq.
__global__ __launch_bounds__(512) void kNODE(
    const float* __restrict__ video, const float* __restrict__ Wv,
    const float* __restrict__ bvp,
    const float* __restrict__ We, const float* __restrict__ be,
    const float* __restrict__ vmask,
    const int* __restrict__ word_ids, const int* __restrict__ char_ids,
    const float* __restrict__ word_emb, const float* __restrict__ char_emb,
    const float* __restrict__ W_embed, const float* __restrict__ b_embed,
    const float* __restrict__ q_mask,
    const float* __restrict__ Wq, const float* __restrict__ bq,
    const float* __restrict__ Wk, const float* __restrict__ bk,
    const float* __restrict__ Wvv, const float* __restrict__ bval,
    const float* __restrict__ Ws, const float* __restrict__ bs,
    float* __restrict__ q, float* __restrict__ k,
    float* __restrict__ v, float* __restrict__ sk,
    float* __restrict__ eq)
{
  __shared__ __align__(16) float smem_f[19008];
  float4* ps4 = reinterpret_cast<float4*>(smem_f);
  float* hl = smem_f + 16896;
  float* xe = smem_f + 17952;
  const int blk = blockIdx.x, tid = threadIdx.x;
  const float* Wm[4] = {Wq, Wk, Wvv, Ws};
  const float* bm[4] = {bq, bk, bval, bs};
  float* om[4] = {q, k, v, sk};

  if (blk < 256) {
    const int r0 = blk * 8;
    {   // stage 8 video rows into padded Vl
      const float4* src = reinterpret_cast<const float4*>(video + (size_t)r0 * 1024);
      #pragma unroll
      for (int i = 0; i < 4; ++i) {
        const int idx4 = tid + i * 512;
        const int r = idx4 >> 8, f = idx4 & 255;
        *reinterpret_cast<float4*>(&smem_f[r * 1028 + f * 4]) = src[r * 256 + f];
      }
    }
    __syncthreads();
    const int c4 = tid & 31, ks = tid >> 5;     // ks: 16-way K-split
    float4 acc[8];
    #pragma unroll
    for (int r = 0; r < 8; ++r) acc[r] = float4{0.f, 0.f, 0.f, 0.f};
    {
      const float4* W4 = reinterpret_cast<const float4*>(Wv) + c4;
      for (int kc = 0; kc < 16; ++kc) {
        const int k0 = ks * 64 + kc * 4;
        const float4 w0 = W4[(size_t)(k0 + 0) * 32];
        const float4 w1 = W4[(size_t)(k0 + 1) * 32];
        const float4 w2 = W4[(size_t)(k0 + 2) * 32];
        const float4 w3 = W4[(size_t)(k0 + 3) * 32];
        #pragma unroll
        for (int r = 0; r < 8; ++r) {
          const float4 rv = *reinterpret_cast<const float4*>(&smem_f[r * 1028 + k0]);
          FMA4(acc[r], rv.x, w0); FMA4(acc[r], rv.y, w1);
          FMA4(acc[r], rv.z, w2); FMA4(acc[r], rv.w, w3);
        }
      }
    }
    __syncthreads();                            // Vl reads done -> ps may overwrite
    #pragma unroll
    for (int r = 0; r < 8; ++r) ps4[(ks * 8 + r) * 33 + c4] = acc[r];
    __syncthreads();
    if (tid < 256) {                            // reduce 16 K-splits + bias -> hl
      const int r = tid >> 5, c = tid & 31;
      float4 s = reinterpret_cast<const float4*>(bvp)[c];
      #pragma unroll
      for (int ke = 0; ke < 16; ++ke) {
        const float4 p = ps4[(ke * 8 + r) * 33 + c];
        s.x += p.x; s.y += p.y; s.z += p.z; s.w += p.w;
      }
      *reinterpret_cast<float4*>(&hl[r * 132 + c * 4]) = s;
    }
    __syncthreads();
    #pragma unroll
    for (int r = 0; r < 8; ++r) acc[r] = float4{0.f, 0.f, 0.f, 0.f};
    {
      const float4* We4 = reinterpret_cast<const float4*>(We) + c4;
      #pragma unroll
      for (int kc = 0; kc < 2; ++kc) {
        const int k0 = ks * 8 + kc * 4;
        const float4 w0 = We4[(size_t)(k0 + 0) * 32];
        const float4 w1 = We4[(size_t)(k0 + 1) * 32];
        const float4 w2 = We4[(size_t)(k0 + 2) * 32];
        const float4 w3 = We4[(size_t)(k0 + 3) * 32];
        #pragma unroll
        for (int r = 0; r < 8; ++r) {
          const float4 rv = *reinterpret_cast<const float4*>(&hl[r * 132 + k0]);
          FMA4(acc[r], rv.x, w0); FMA4(acc[r], rv.y, w1);
          FMA4(acc[r], rv.z, w2); FMA4(acc[r], rv.w, w3);
        }
      }
    }
    #pragma unroll
    for (int r = 0; r < 8; ++r) ps4[(ks * 8 + r) * 33 + c4] = acc[r];
    __syncthreads();
    if (tid < 256) {                            // reduce + bias + relu*mask -> xe
      const int r = tid >> 5, c = tid & 31;
      float4 s = reinterpret_cast<const float4*>(be)[c];
      #pragma unroll
      for (int ke = 0; ke < 16; ++ke) {
        const float4 p = ps4[(ke * 8 + r) * 33 + c];
        s.x += p.x; s.y += p.y; s.z += p.z; s.w += p.w;
      }
      const float mk = vmask[r0 + r];
      s.x = fmaxf(s.x, 0.f) * mk; s.y = fmaxf(s.y, 0.f) * mk;
      s.z = fmaxf(s.z, 0.f) * mk; s.w = fmaxf(s.w, 0.f) * mk;
      *reinterpret_cast<float4*>(&xe[r * 132 + c * 4]) = s;
    }
    __syncthreads();
    const int m = ks >> 2, keP = ks & 3;
    #pragma unroll
    for (int r = 0; r < 8; ++r) acc[r] = float4{0.f, 0.f, 0.f, 0.f};
    {
      const float4* Wp4 = reinterpret_cast<const float4*>(Wm[m]) + c4;
      #pragma unroll
      for (int kc = 0; kc < 8; ++kc) {
        const int k0 = keP * 32 + kc * 4;
        const float4 w0 = Wp4[(size_t)(k0 + 0) * 32];
        const float4 w1 = Wp4[(size_t)(k0 + 1) * 32];
        const float4 w2 = Wp4[(size_t)(k0 + 2) * 32];
        const float4 w3 = Wp4[(size_t)(k0 + 3) * 32];
        #pragma unroll
        for (int r = 0; r < 8; ++r) {
          const float4 rv = *reinterpret_cast<const float4*>(&xe[r * 132 + k0]);
          FMA4(acc[r], rv.x, w0); FMA4(acc[r], rv.y, w1);
          FMA4(acc[r], rv.z, w2); FMA4(acc[r], rv.w, w3);
        }
      }
    }
    #pragma unroll
    for (int r = 0; r < 8; ++r) ps4[(ks * 8 + r) * 33 + c4] = acc[r];
    __syncthreads();
    #pragma unroll
    for (int it = 0; it < 2; ++it) {            // reduce 4 K-splits per (m,r,c4)
      const int id = tid + it * 512;
      const int mm = id >> 8, r = (id >> 5) & 7, c = id & 31;
      float4 s = reinterpret_cast<const float4*>(bm[mm])[c];
      #pragma unroll
      for (int ke = 0; ke < 4; ++ke) {
        const float4 p = ps4[((mm * 4 + ke) * 8 + r) * 33 + c];
        s.x += p.x; s.y += p.y; s.z += p.z; s.w += p.w;
      }
      const int vr = r0 + r;
      const int node = (vr >> 8) * 257 + 1 + (vr & 255);
      *reinterpret_cast<float4*>(om[mm] + (size_t)node * 128 + 4 * c) = s;
    }
  } else {
    // ---- query row (256 active threads; barriers unconditional) ----
    const int qi = blk - 256;
    const int b = qi / 20, lq = qi - b * 20;
    float* emb = smem_f;          // [352]
    float* ps  = emb + 352;       // [2][128]
    float* hq  = emb + 608;       // [128]
    float* pe  = emb + 736;       // [2][128]
    const int wid = word_ids[b * LQ_ + lq];
    for (int m2 = tid; m2 < 300; m2 += 512) emb[m2] = word_emb[(size_t)wid * 300 + m2];
    if (tid < 50) {
      float s = 0.f;
      #pragma unroll
      for (int l = 0; l < 10; ++l) {
        const int cid = char_ids[(b * LQ_ + lq) * 10 + l];
        s += char_emb[cid * 50 + tid];
      }
      emb[300 + tid] = s * 0.1f;
    }
    __syncthreads();
    const int j = tid & 127, half = tid >> 7;
    if (tid < 256) {
      float a = 0.f;
      const float* Wcol = W_embed + (size_t)(half * 175) * 128 + j;
      const float* eh = emb + half * 175;
      #pragma unroll 5
      for (int m2 = 0; m2 < 175; ++m2) a += eh[m2] * Wcol[(size_t)m2 * 128];
      ps[half * 128 + j] = a;
    }
    __syncthreads();
    if (tid < 128) hq[tid] = ps[tid] + ps[128 + tid] + b_embed[tid];
    __syncthreads();
    if (tid < 256) {
      float e = 0.f;
      #pragma unroll 8
      for (int kk = 0; kk < 64; ++kk)
        e += hq[half * 64 + kk] * We[(half * 64 + kk) * 128 + j];
      pe[half * 128 + j] = e;
    }
    __syncthreads();
    if (tid < 128) {
      float ev = pe[tid] + pe[128 + tid] + be[tid];
      ev = fmaxf(ev, 0.f) * q_mask[b * LQ_ + lq];
      eq[(size_t)qi * 128 + tid] = ev;
    }
  }
}

// ---------------- edge multiplicity (verified round 1) -----------------------
__device__ __forceinline__ float cntf(int dnode, int s) {
  if (dnode == 256) return (s == 0 ? 1.f : 0.f) + (s == 255 ? 1.f : 0.f);
  float c = (s != dnode) ? 1.f : 0.f;          // semantic all-pairs (nodes 0..255)
  if (s == 0) c += 1.f;                        // query->segment
  if (s == dnode - 1) c += 2.f;                // qe chain + temporal h=1 fwd
  if (s == dnode + 1 && dnode <= 254) c += 1.f;// temporal h=1 bwd
  if (s == dnode - 2 && dnode >= 2) c += 1.f;  // temporal h=2 fwd
  if (s == dnode + 2 && dnode <= 253) c += 1.f;// temporal h=2 bwd
  return c;
}

// ---------------- kATTN: scalar-logit attention partials ---------------------
// Algebra: out_start only needs Σ_h (1/den_h)·Σ_s w_s·Vst_h[s] where
// Vst_h[s] = V[s][h16..]·Wst[h16..]. PV phase collapses to 2 FMA/s; partials
// are 3 scalars per (dst,h,chunk). Grid (8,8,8), 256 thr, thread=(dd,h).
__global__ __launch_bounds__(256) void kATTN(
    const float* __restrict__ q, const float* __restrict__ k,
    const float* __restrict__ v, const float* __restrict__ eq,
    const float* __restrict__ Wk, const float* __restrict__ bk,
    const float* __restrict__ Wvv, const float* __restrict__ bval,
    const float* __restrict__ W_start, const float* __restrict__ W_end,
    float* __restrict__ nst_p, float* __restrict__ nen_p,
    float* __restrict__ den_p)
{
  __shared__ float Kl[32][128];
  __shared__ float Vl[32][128];
  __shared__ float m0[128];
  __shared__ float vstl[32][8];
  __shared__ float venl[32][8];
  const int d0 = blockIdx.x * 32;
  const int y  = blockIdx.y;
  const int b  = blockIdx.z;
  const int tid = threadIdx.x;
  const int base = b * 257;
  const int s0 = y * 32;
  {
    const float4* ksrc = reinterpret_cast<const float4*>(k + (size_t)(base + s0) * 128);
    const float4* vsrc = reinterpret_cast<const float4*>(v + (size_t)(base + s0) * 128);
    float4* kd = reinterpret_cast<float4*>(Kl);
    float4* vd = reinterpret_cast<float4*>(Vl);
    #pragma unroll
    for (int i = 0; i < 4; ++i) {
      kd[tid + i * 256] = ksrc[tid + i * 256];
      vd[tid + i * 256] = vsrc[tid + i * 256];
    }
  }
  if (y == 0 && tid < 128) {
    float s = 0.f;
    #pragma unroll 4
    for (int lq = 0; lq < LQ_; ++lq) s += eq[((size_t)b * LQ_ + lq) * 128 + tid];
    m0[tid] = s * (1.f / LQ_);
  }
  const int dd = tid >> 3, h = tid & 7;
  const int dnode = d0 + dd + 1;
  const float* qrow = q + (size_t)(base + dnode) * 128 + h * 16;
  const float4 qq0 = *(const float4*)(qrow + 0);
  const float4 qq1 = *(const float4*)(qrow + 4);
  const float4 qq2 = *(const float4*)(qrow + 8);
  const float4 qq3 = *(const float4*)(qrow + 12);
  __syncthreads();
  if (y == 0) {                        // overwrite row 0 with node-0 K/V
    const int j = tid & 127, half = tid >> 7;
    const float* W = half ? Wvv : Wk;
    float acc = half ? bval[j] : bk[j];
    #pragma unroll 8
    for (int kk = 0; kk < 128; ++kk) acc += m0[kk] * W[kk * 128 + j];
    if (half) Vl[0][j] = acc; else Kl[0][j] = acc;
  }
  __syncthreads();
  {                                    // per-(s,h) V·Wst / V·Wen scalars
    const int sv = tid >> 3, hv = tid & 7;
    const float* vr = &Vl[sv][hv * 16];
    const float* wst = W_start + hv * 16;
    const float* wen = W_end + hv * 16;
    float a = 0.f, e = 0.f;
    #pragma unroll
    for (int i = 0; i < 16; ++i) { a += vr[i] * wst[i]; e += vr[i] * wen[i]; }
    vstl[sv][hv] = a; venl[sv][hv] = e;
  }
  __syncthreads();

  float den = 0.f, nst = 0.f, nen = 0.f;
  #pragma unroll 4
  for (int s = 0; s < 32; ++s) {
    const float* krow = &Kl[s][h * 16];
    const float4 k0 = *(const float4*)(krow + 0);
    const float4 k1 = *(const float4*)(krow + 4);
    const float4 k2 = *(const float4*)(krow + 8);
    const float4 k3 = *(const float4*)(krow + 12);
    float dt = qq0.x*k0.x + qq0.y*k0.y + qq0.z*k0.z + qq0.w*k0.w
             + qq1.x*k1.x + qq1.y*k1.y + qq1.z*k1.z + qq1.w*k1.w
             + qq2.x*k2.x + qq2.y*k2.y + qq2.z*k2.z + qq2.w*k2.w
             + qq3.x*k3.x + qq3.y*k3.y + qq3.z*k3.z + qq3.w*k3.w;
    const float c = cntf(dnode, s0 + s);
    const float pw = c * __expf(dt * 0.25f);
    den += pw;
    nst += pw * vstl[s][h];
    nen += pw * venl[s][h];
  }
  const size_t pb = (((size_t)y * 8 + b) * 256 + d0 + dd) * 8 + h;
  nst_p[pb] = nst; nen_p[pb] = nen; den_p[pb] = den;
}

// ---------------- kRED: scalar combine + skip-dot + logits -------------------
__global__ __launch_bounds__(256) void kRED(
    const float* __restrict__ nst_p, const float* __restrict__ nen_p,
    const float* __restrict__ den_p, const float* __restrict__ sk,
    const float* __restrict__ W_start, const float* __restrict__ b_start,
    const float* __restrict__ W_end, const float* __restrict__ b_end,
    float* __restrict__ out)
{
  __shared__ float attst[16], atten[16];
  __shared__ float red[16][2][2];
  const int d0 = blockIdx.x * 16;
  const int b = blockIdx.y;
  const int tid = threadIdx.x;
  const int base = b * 257;
  if (tid < 128) {                     // (dd 0..15, h 0..7): sum chunks, /den
    const int dd = tid >> 3, h = tid & 7;
    const int dst = d0 + dd;
    float den = 0.f, nst = 0.f, nen = 0.f;
    #pragma unroll
    for (int y = 0; y < 8; ++y) {
      const size_t pb = (((size_t)y * 8 + b) * 256 + dst) * 8 + h;
      nst += nst_p[pb]; nen += nen_p[pb]; den += den_p[pb];
    }
    float rst = nst / (den + 1e-16f);
    float ren = nen / (den + 1e-16f);
    #pragma unroll
    for (int off = 1; off < 8; off <<= 1) {
      rst += __shfl_xor(rst, off);
      ren += __shfl_xor(ren, off);
    }
    if (h == 0) { attst[dd] = rst; atten[dd] = ren; }
  }
  __syncthreads();
  const int jB = tid & 127, shB = tid >> 7;
  const float wst = W_start[jB], wen = W_end[jB];
  #pragma unroll
  for (int dd8 = 0; dd8 < 8; ++dd8) {
    const int dd = shB * 8 + dd8;
    const int dst = d0 + dd;
    const float o = sk[(size_t)(base + dst + 1) * 128 + jB];
    float psum = o * wst, pesum = o * wen;
    #pragma unroll
    for (int off = 1; off < 64; off <<= 1) {
      psum += __shfl_xor(psum, off);
      pesum += __shfl_xor(pesum, off);
    }
    if ((tid & 63) == 0) { red[dd][jB >> 6][0] = psum; red[dd][jB >> 6][1] = pesum; }
  }
  __syncthreads();
  if (tid < 16) {
    out[b * 256 + d0 + tid]        = red[tid][0][0] + red[tid][1][0] + attst[tid] + b_start[0];
    out[2048 + b * 256 + d0 + tid] = red[tid][0][1] + red[tid][1][1] + atten[tid] + b_end[0];
  }
}

extern "C" void kernel_launch(void* const* d_in, const int* in_sizes, int n_in,
                              void* d_out, int out_size, void* d_ws, size_t ws_size,
                              hipStream_t stream) {
  const int*   word_ids = (const int*)d_in[0];
  const int*   char_ids = (const int*)d_in[1];
  const float* video    = (const float*)d_in[2];
  const float* v_mask   = (const float*)d_in[3];
  const float* q_mask   = (const float*)d_in[4];
  const float* word_emb = (const float*)d_in[5];
  const float* char_emb = (const float*)d_in[6];
  const float* W_embed  = (const float*)d_in[7];
  const float* b_embed  = (const float*)d_in[8];
  const float* W_vproj  = (const float*)d_in[9];
  const float* b_vproj  = (const float*)d_in[10];
  const float* W_enc    = (const float*)d_in[11];
  const float* b_enc    = (const float*)d_in[12];
  const float* Wq       = (const float*)d_in[13];
  const float* bq       = (const float*)d_in[14];
  const float* Wk       = (const float*)d_in[15];
  const float* bk       = (const float*)d_in[16];
  const float* Wv       = (const float*)d_in[17];
  const float* bv       = (const float*)d_in[18];
  const float* Wskip    = (const float*)d_in[19];
  const float* bskip    = (const float*)d_in[20];
  const float* W_start  = (const float*)d_in[21];
  const float* b_start  = (const float*)d_in[22];
  const float* W_end    = (const float*)d_in[23];
  const float* b_end    = (const float*)d_in[24];

  float* q     = (float*)d_ws;
  float* k     = q  + NN_ * DIM_;
  float* v     = k  + NN_ * DIM_;
  float* sk    = v  + NN_ * DIM_;
  float* eq    = sk + NN_ * DIM_;                    // 160*128
  float* nst_p = eq + 160 * 128;                     // 8*8*256*8 = 128K floats
  float* nen_p = nst_p + 131072;
  float* den_p = nen_p + 131072;

  hipLaunchKernelGGL(kNODE, dim3(416), dim3(512), 0, stream,
    video, W_vproj, b_vproj, W_enc, b_enc, v_mask,
    word_ids, char_ids, word_emb, char_emb, W_embed, b_embed, q_mask,
    Wq, bq, Wk, bk, Wv, bv, Wskip, bskip, q, k, v, sk, eq);
  hipLaunchKernelGGL(kATTN, dim3(8, 8, 8), dim3(256), 0, stream,
    q, k, v, eq, Wk, bk, Wv, bv, W_start, W_end, nst_p, nen_p, den_p);
  hipLaunchKernelGGL(kRED, dim3(16, 8), dim3(256), 0, stream,
    nst_p, nen_p, den_p, sk, W_start, b_start, W_end, b_end, (float*)d_out);
}